// Round 6
// baseline (1712.340 us; speedup 1.0000x reference)
//
#include <hip/hip_runtime.h>
#include <hip/hip_bf16.h>
#include <stdint.h>

#define S_LEN 2048
#define D_HEAD 64
#define NBH 64            // B*H = 4*16
#define KBLK 64
#define NITER (S_LEN / KBLK)   // 32

// Q pre-scale: 1/sqrt(64) * log2(e), so scores feed exp2f directly
#define QSCALE 0.1803368801111244f

typedef __attribute__((ext_vector_type(8))) short short8;  // 8 x bf16
typedef __attribute__((ext_vector_type(4))) float f32x4;

__device__ __forceinline__ short f2b(float x) {  // fp32 -> bf16 RNE
  unsigned u = __float_as_uint(x);
  unsigned r = 0x7FFFu + ((u >> 16) & 1u);
  return (short)((u + r) >> 16);
}
__device__ __forceinline__ unsigned pack2bf(float e0, float e1) {
  union { __hip_bfloat162 h; unsigned u; } cv;
  cv.h = __float22bfloat162_rn(float2{e0, e1});
  return cv.u;   // e0 in low 16, e1 in high 16
}

// Detect mask element width: int32/fp32 words are in {0,1,0x3F800000};
// byte-packed bools give other word values w.h.p.
__global__ void detect_mask_kernel(const unsigned* m, int* flag) {
  unsigned v = m[blockIdx.x * 256 + threadIdx.x];
  if (v != 0u && v != 1u && v != 0x3F800000u) atomicOr(flag, 1);
}

// fp32 -> bf16, linear (for K)
__global__ void __launch_bounds__(256) convK_kernel(
    const float* __restrict__ in, short* __restrict__ out) {
  size_t i = ((size_t)blockIdx.x * 256 + threadIdx.x) * 8;
  float4 a = ((const float4*)(in + i))[0];
  float4 b = ((const float4*)(in + i))[1];
  short8 v;
  v[0] = f2b(a.x); v[1] = f2b(a.y); v[2] = f2b(a.z); v[3] = f2b(a.w);
  v[4] = f2b(b.x); v[5] = f2b(b.y); v[6] = f2b(b.z); v[7] = f2b(b.w);
  *(short8*)(out + i) = v;
}

// fp32 V[bh][s][d] -> bf16 Vt[bh][d][s]
__global__ void __launch_bounds__(256) convVT_kernel(
    const float* __restrict__ V, short* __restrict__ out) {
  __shared__ __align__(16) short t[64 * 72];
  int tid = threadIdx.x;
  int kb = blockIdx.x * 64, bh = blockIdx.y;
  const float* src = V + ((size_t)bh * S_LEN + kb) * D_HEAD;
#pragma unroll
  for (int j = 0; j < 4; ++j) {
    int key = j * 16 + (tid >> 4), d0 = (tid & 15) * 4;
    float4 f = *(const float4*)(src + (size_t)key * D_HEAD + d0);
    t[(d0 + 0) * 72 + key] = f2b(f.x);
    t[(d0 + 1) * 72 + key] = f2b(f.y);
    t[(d0 + 2) * 72 + key] = f2b(f.z);
    t[(d0 + 3) * 72 + key] = f2b(f.w);
  }
  __syncthreads();
  int row = tid >> 2, seg = tid & 3;
  short8 v0 = *(const short8*)(t + row * 72 + seg * 16);
  short8 v1 = *(const short8*)(t + row * 72 + seg * 16 + 8);
  short* dst = out + (size_t)bh * D_HEAD * S_LEN + (size_t)row * S_LEN + kb + seg * 16;
  *(short8*)dst = v0;
  *(short8*)(dst + 8) = v1;
}

// ======================= FAST PATH: barrier-free waves =======================
// One wave owns 16 Q-rows. Swapped QK^T (A=K, B=Q) makes lane = q-row for
// mask/exp/rowsum (all lane-local). P transposed for PV via a 2KB per-wave
// private LDS tile (same-wave DS ordering; no s_barrier in this kernel).
template <bool BYTEMASK>
__device__ __forceinline__ void attn_fast(
    char* Pw, float* linvw, const float* Qg, const void* maskg,
    const short* Kbf, const short* Vtb, float* ctxg, float* attng,
    int g) {

  const int l = threadIdx.x & 63;
  const int li = l & 15, hi = l >> 4;
  const int bh = g >> 7;
  const int qbase = (g & 127) * 16;

  const short* Kbp = Kbf + (size_t)bh * S_LEN * D_HEAD;        // 128B rows
  const short* Vtp = Vtb + (size_t)bh * D_HEAD * S_LEN;        // 4KB rows
  const float* Qp  = Qg + ((size_t)bh * S_LEN + qbase) * D_HEAD;
  float* arow = attng + ((size_t)bh * S_LEN + qbase + li) * S_LEN;
  float* ctxp = ctxg + ((size_t)bh * S_LEN + qbase) * D_HEAD;

  // ---- Q fragments (B-operand): lane li = q-row, hi = k-segment ----
  short8 qf0, qf1;
  {
    const float* qsrc = Qp + li * D_HEAD + hi * 8;
    float4 a = *(const float4*)(qsrc);
    float4 b = *(const float4*)(qsrc + 4);
    float4 c = *(const float4*)(qsrc + 32);
    float4 d = *(const float4*)(qsrc + 36);
    qf0[0] = f2b(a.x * QSCALE); qf0[1] = f2b(a.y * QSCALE);
    qf0[2] = f2b(a.z * QSCALE); qf0[3] = f2b(a.w * QSCALE);
    qf0[4] = f2b(b.x * QSCALE); qf0[5] = f2b(b.y * QSCALE);
    qf0[6] = f2b(b.z * QSCALE); qf0[7] = f2b(b.w * QSCALE);
    qf1[0] = f2b(c.x * QSCALE); qf1[1] = f2b(c.y * QSCALE);
    qf1[2] = f2b(c.z * QSCALE); qf1[3] = f2b(c.w * QSCALE);
    qf1[4] = f2b(d.x * QSCALE); qf1[5] = f2b(d.y * QSCALE);
    qf1[6] = f2b(d.z * QSCALE); qf1[7] = f2b(d.w * QSCALE);
  }

  const unsigned char* mrowB =
      (const unsigned char*)maskg + (size_t)(((size_t)bh * S_LEN + qbase + li)) * S_LEN;
  const int* mrowI = (const int*)maskg + (size_t)(((size_t)bh * S_LEN + qbase + li)) * S_LEN;

  // K fragments for one 64-key tile: kf[ct][h] = K[kbase+ct*16+li][dims h*32+hi*8 ..+8]
  auto loadK = [&](int i, short8 kf[4][2]) {
    const short* kb = Kbp + (size_t)i * KBLK * D_HEAD + (size_t)li * D_HEAD + hi * 8;
#pragma unroll
    for (int ct = 0; ct < 4; ++ct) {
      const short* kr = kb + ct * 16 * D_HEAD;
      kf[ct][0] = *(const short8*)(kr);
      kf[ct][1] = *(const short8*)(kr + 32);
    }
  };

  // swapped QK^T: sa[ct] = S^T tile; lane: row=key(hi*4+reg within tile), col=li=qrow
  auto qkt = [&](const short8 kf[4][2], f32x4* sa) {
#pragma unroll
    for (int ct = 0; ct < 4; ++ct) {
      f32x4 z = {0.f, 0.f, 0.f, 0.f};
      sa[ct] = __builtin_amdgcn_mfma_f32_16x16x32_bf16(kf[ct][0], qf0, z, 0, 0, 0);
      sa[ct] = __builtin_amdgcn_mfma_f32_16x16x32_bf16(kf[ct][1], qf1, sa[ct], 0, 0, 0);
    }
  };

  auto loadPred = [&](int i) -> unsigned {
    unsigned pb = 0;
    if constexpr (BYTEMASK) {
#pragma unroll
      for (int ct = 0; ct < 4; ++ct) {
        unsigned m = *(const unsigned*)(mrowB + i * KBLK + ct * 16 + hi * 4);
        pb |= ((m * 0x01020408u) >> 24) << (ct * 4);   // bytes {0,1} -> 4 bits
      }
    } else {
#pragma unroll
      for (int ct = 0; ct < 4; ++ct) {
        int4 m = *(const int4*)(mrowI + i * KBLK + ct * 16 + hi * 4);
        unsigned p4 = (m.x != 0 ? 1u : 0u) | (m.y != 0 ? 2u : 0u) |
                      (m.z != 0 ? 4u : 0u) | (m.w != 0 ? 8u : 0u);
        pb |= p4 << (ct * 4);
      }
    }
    return pb;
  };

  // ================= pass 1: denominators; pred -> 16 VGPRs =================
  unsigned pred[16];
  float lsum = 0.f;
#pragma unroll
  for (int i = 0; i < NITER; ++i) {
    short8 kf[4][2];
    loadK(i, kf);
    unsigned pb = loadPred(i);
    f32x4 sa[4];
    qkt(kf, sa);
#pragma unroll
    for (int ct = 0; ct < 4; ++ct)
#pragma unroll
      for (int reg = 0; reg < 4; ++reg) {
        float e = ((pb >> (ct * 4 + reg)) & 1u) ? 0.f : exp2f(sa[ct][reg]);
        lsum += e;
      }
    if (i & 1) pred[i >> 1] |= pb << 16; else pred[i >> 1] = pb;
  }

  // combine the 4 hi-lanes of each q-row
  lsum += __shfl_xor(lsum, 16);
  lsum += __shfl_xor(lsum, 32);
  const float linv = 1.0f / lsum;          // lane-local: row li
  if (l < 16) linvw[li] = linv;            // stash for ctx epilogue (row = hi*4+reg)
  float linv4[4];
#pragma unroll
  for (int r = 0; r < 4; ++r) linv4[r] = linvw[hi * 4 + r];

  // ================= pass 2: recompute S, write attn, PV =================
  f32x4 po[4];
#pragma unroll
  for (int ct2 = 0; ct2 < 4; ++ct2) po[ct2] = f32x4{0.f, 0.f, 0.f, 0.f};

#pragma unroll
  for (int i = 0; i < NITER; ++i) {
    short8 kf[4][2];
    loadK(i, kf);
    f32x4 sa[4];
    qkt(kf, sa);
    const unsigned pb = (pred[i >> 1] >> ((i & 1) * 16)) & 0xffffu;
#pragma unroll
    for (int ct = 0; ct < 4; ++ct) {
      float e0 = ((pb >> (ct * 4 + 0)) & 1u) ? 0.f : exp2f(sa[ct][0]);
      float e1 = ((pb >> (ct * 4 + 1)) & 1u) ? 0.f : exp2f(sa[ct][1]);
      float e2 = ((pb >> (ct * 4 + 2)) & 1u) ? 0.f : exp2f(sa[ct][2]);
      float e3 = ((pb >> (ct * 4 + 3)) & 1u) ? 0.f : exp2f(sa[ct][3]);
      float4 st = {e0 * linv, e1 * linv, e2 * linv, e3 * linv};
      *(float4*)(arow + i * KBLK + ct * 16 + hi * 4) = st;   // 16 rows x 64B dense
      // pack unnormalized P (bf16) into per-wave LDS, XOR-swizzled:
      // byte(r=li, key k): r*128 + ((k/8)^(r&7))*16 + (k%8)*2 ; here k0=ct*16+hi*4
      uint2 pk;
      pk.x = pack2bf(e0, e1);
      pk.y = pack2bf(e2, e3);
      *(uint2*)(Pw + li * 128 + (((ct * 2 + (hi >> 1)) ^ (li & 7)) << 4) +
                ((hi & 1) * 8)) = pk;
    }
    // PV: po[ct2](16 qrow x 16 d) += P(16x32) * V(32x16) over 2 k-slices
#pragma unroll
    for (int ks = 0; ks < 2; ++ks) {
      short8 pA = *(const short8*)(Pw + li * 128 + ((((ks * 4) + hi) ^ (li & 7)) << 4));
#pragma unroll
      for (int ct2 = 0; ct2 < 4; ++ct2) {
        const short* vr = Vtp + (size_t)(ct2 * 16 + li) * S_LEN + i * KBLK + ks * 32 + hi * 8;
        short8 vB = *(const short8*)vr;
        po[ct2] = __builtin_amdgcn_mfma_f32_16x16x32_bf16(pA, vB, po[ct2], 0, 0, 0);
      }
    }
  }

  // epilogue: ctx[qrow = hi*4+reg][d = ct2*16+li] = po * linv(qrow)
#pragma unroll
  for (int ct2 = 0; ct2 < 4; ++ct2)
#pragma unroll
    for (int reg = 0; reg < 4; ++reg)
      ctxp[(size_t)(hi * 4 + reg) * D_HEAD + ct2 * 16 + li] = po[ct2][reg] * linv4[reg];
}

__global__ void __launch_bounds__(256, 3)
attn_fast_kernel(const float* Q, const void* M, const short* Kbf, const short* Vtb,
                 float* ctx, float* attn, const int* flag) {
  __shared__ __align__(16) char smem[4 * 2048 + 4 * 64];
  const int w = threadIdx.x >> 6;
  char* Pw = smem + w * 2048;
  float* linvw = (float*)(smem + 4 * 2048 + w * 64);
  int bid = blockIdx.x;
  int s = ((bid & 7) << 8) | (bid >> 3);   // XCD-bijective swizzle (2048 = 8*256)
  int g = s * 4 + w;                        // global wave id: bh = g>>7, strip = g&127
  if (*flag)
    attn_fast<true>(Pw, linvw, Q, M, Kbf, Vtb, ctx, attn, g);
  else
    attn_fast<false>(Pw, linvw, Q, M, Kbf, Vtb, ctx, attn, g);
}

// ======================= FALLBACK (round-2 body; no workspace needed) =======================
#define FK_OFF  0
#define FVT_OFF 16384
#define FP_OFF  24576
#define FMB_OFF 28672
#define FLP_OFF 36864
#define FSMEM_BYTES 37120

__device__ __forceinline__ int swz1(int row, int b) {
  return row * 128 + (b ^ ((row & 7) << 4));
}
__device__ __forceinline__ int swz2(int row, int b) {
  return row * 128 + (b ^ (((row >> 1) & 7) << 4));
}

template <bool BYTEMASK>
__device__ __forceinline__ void attn_body(
    char* smem, const float* Qg, const float* Kg, const float* Vg,
    const void* maskg, float* ctxg, float* attng) {

  const int tid = threadIdx.x;
  const int w = tid >> 6, l = tid & 63;
  const int lg = l >> 4, li = l & 15;
  const int rh = w >> 1, ch = w & 1;
  const int qb = blockIdx.x, bh = blockIdx.y;
  const int qbase = qb * 32;

  const float* Qp = Qg + ((size_t)bh * S_LEN + qbase) * D_HEAD;
  const float* Kp = Kg + (size_t)bh * S_LEN * D_HEAD;
  const float* Vp = Vg + (size_t)bh * S_LEN * D_HEAD;
  float* attnp = attng + ((size_t)bh * S_LEN + qbase) * S_LEN;
  float* ctxp  = ctxg  + ((size_t)bh * S_LEN + qbase) * D_HEAD;
  const size_t mrow0 = ((size_t)bh * S_LEN + qbase) * S_LEN;

  auto stageK = [&](int it, int buf) {
    char* kb = smem + FK_OFF + buf * 8192;
    int key = tid >> 2, seg = tid & 3;
    const float* src = Kp + ((size_t)(it * KBLK + key)) * D_HEAD + seg * 16;
    float4 f0 = ((const float4*)src)[0];
    float4 f1 = ((const float4*)src)[1];
    float4 f2 = ((const float4*)src)[2];
    float4 f3 = ((const float4*)src)[3];
    short8 v0, v1;
    v0[0] = f2b(f0.x); v0[1] = f2b(f0.y); v0[2] = f2b(f0.z); v0[3] = f2b(f0.w);
    v0[4] = f2b(f1.x); v0[5] = f2b(f1.y); v0[6] = f2b(f1.z); v0[7] = f2b(f1.w);
    v1[0] = f2b(f2.x); v1[1] = f2b(f2.y); v1[2] = f2b(f2.z); v1[3] = f2b(f2.w);
    v1[4] = f2b(f3.x); v1[5] = f2b(f3.y); v1[6] = f2b(f3.z); v1[7] = f2b(f3.w);
    *(short8*)(kb + swz1(key, seg * 32)) = v0;
    *(short8*)(kb + swz1(key, seg * 32 + 16)) = v1;
  };

  auto stageVt = [&](int it) {
    char* vb = smem + FVT_OFF;
    int key = l, db = w;
    const float* src = Vp + ((size_t)(it * KBLK + key)) * D_HEAD + db * 16;
#pragma unroll
    for (int j = 0; j < 4; ++j) {
      float4 f = ((const float4*)src)[j];
      int dd = db * 16 + j * 4;
      *(short*)(vb + swz1(dd + 0, key * 2)) = f2b(f.x);
      *(short*)(vb + swz1(dd + 1, key * 2)) = f2b(f.y);
      *(short*)(vb + swz1(dd + 2, key * 2)) = f2b(f.z);
      *(short*)(vb + swz1(dd + 3, key * 2)) = f2b(f.w);
    }
  };

  auto loadMask = [&](int it, unsigned* m) {
#pragma unroll
    for (int reg = 0; reg < 4; ++reg) {
      int rw = rh * 16 + lg * 4 + reg;
#pragma unroll
      for (int ct = 0; ct < 2; ++ct) {
        size_t idx = mrow0 + (size_t)rw * S_LEN + it * KBLK + ch * 32 + ct * 16 + li;
        if constexpr (BYTEMASK)
          m[ct * 4 + reg] = (unsigned)((const unsigned char*)maskg)[idx];
        else
          m[ct * 4 + reg] = ((const unsigned*)maskg)[idx];
      }
    }
  };

  auto qkt = [&](f32x4* accs, const short8* qf, int buf) {
    char* kb = smem + FK_OFF + buf * 8192;
#pragma unroll
    for (int ct = 0; ct < 2; ++ct) {
      int key = ch * 32 + ct * 16 + li;
      short8 b0 = *(const short8*)(kb + swz1(key, lg * 16));
      short8 b1 = *(const short8*)(kb + swz1(key, 64 + lg * 16));
      accs[ct] = __builtin_amdgcn_mfma_f32_16x16x32_bf16(qf[0], b0, accs[ct], 0, 0, 0);
      accs[ct] = __builtin_amdgcn_mfma_f32_16x16x32_bf16(qf[1], b1, accs[ct], 0, 0, 0);
    }
  };

  stageK(0, 0);
  unsigned mc[8];
  loadMask(0, mc);
  {
    int rw = tid >> 3, seg = tid & 7;
    const float* src = Qp + rw * D_HEAD + seg * 8;
    float4 a = ((const float4*)src)[0];
    float4 b = ((const float4*)src)[1];
    short8 v;
    v[0] = f2b(a.x); v[1] = f2b(a.y); v[2] = f2b(a.z); v[3] = f2b(a.w);
    v[4] = f2b(b.x); v[5] = f2b(b.y); v[6] = f2b(b.z); v[7] = f2b(b.w);
    *(short8*)(smem + FP_OFF + swz1(rw, seg * 16)) = v;
  }
  __syncthreads();
  short8 qfrag[2];
  {
    int rw = rh * 16 + li;
    qfrag[0] = *(const short8*)(smem + FP_OFF + swz1(rw, lg * 16));
    qfrag[1] = *(const short8*)(smem + FP_OFF + swz1(rw, 64 + lg * 16));
  }
  __syncthreads();

  float l_acc[4] = {0.f, 0.f, 0.f, 0.f};
  for (int it = 0; it < NITER; ++it) {
    const int cb = it & 1, nb = cb ^ 1;
    if (it + 1 < NITER) stageK(it + 1, nb);
    unsigned mn[8];
    if (it + 1 < NITER) loadMask(it + 1, mn);
    f32x4 accs[2] = {{0.f,0.f,0.f,0.f},{0.f,0.f,0.f,0.f}};
    qkt(accs, qfrag, cb);
    unsigned mbyte = 0;
#pragma unroll
    for (int reg = 0; reg < 4; ++reg) {
      float contrib = 0.f;
#pragma unroll
      for (int ct = 0; ct < 2; ++ct) {
        bool pred = mc[ct * 4 + reg] != 0u;
        mbyte |= (unsigned)pred << (ct * 4 + reg);
        float pp = pred ? 0.f : __expf(accs[ct][reg] * 0.125f);
        contrib += pp;
      }
      contrib += __shfl_xor(contrib, 1);
      contrib += __shfl_xor(contrib, 2);
      contrib += __shfl_xor(contrib, 4);
      contrib += __shfl_xor(contrib, 8);
      l_acc[reg] += contrib;
    }
    *(unsigned char*)(smem + FMB_OFF + it * 256 + tid) = (unsigned char)mbyte;
    __syncthreads();
    if (it + 1 < NITER) {
#pragma unroll
      for (int i = 0; i < 8; ++i) mc[i] = mn[i];
    }
  }

  if (li == 0) {
#pragma unroll
    for (int reg = 0; reg < 4; ++reg)
      *(float*)(smem + FLP_OFF + ch * 128 + (rh * 16 + lg * 4 + reg) * 4) = l_acc[reg];
  }
  stageK(0, 0);
  stageVt(0);
  __syncthreads();
  float linv[4];
#pragma unroll
  for (int reg = 0; reg < 4; ++reg) {
    int rw = rh * 16 + lg * 4 + reg;
    linv[reg] = 1.0f / (*(const float*)(smem + FLP_OFF + rw * 4) +
                        *(const float*)(smem + FLP_OFF + 128 + rw * 4));
  }

  f32x4 acco[2] = {{0.f,0.f,0.f,0.f},{0.f,0.f,0.f,0.f}};
  for (int it = 0; it < NITER; ++it) {
    const int cb = it & 1, nb = cb ^ 1;
    if (it > 0) stageVt(it);
    if (it + 1 < NITER) stageK(it + 1, nb);
    f32x4 accs[2] = {{0.f,0.f,0.f,0.f},{0.f,0.f,0.f,0.f}};
    qkt(accs, qfrag, cb);
    unsigned mbyte = *(const unsigned char*)(smem + FMB_OFF + it * 256 + tid);
#pragma unroll
    for (int reg = 0; reg < 4; ++reg) {
      int rw = rh * 16 + lg * 4 + reg;
#pragma unroll
      for (int ct = 0; ct < 2; ++ct) {
        int col = ch * 32 + ct * 16 + li;
        bool pred = (mbyte >> (ct * 4 + reg)) & 1u;
        float pp = pred ? 0.f : __expf(accs[ct][reg] * 0.125f) * linv[reg];
        attnp[(size_t)rw * S_LEN + it * KBLK + col] = pp;
        *(short*)(smem + FP_OFF + swz2(rw, col * 2)) = f2b(pp);
      }
    }
    __syncthreads();
#pragma unroll
    for (int ks = 0; ks < 2; ++ks) {
      int prow = rh * 16 + li;
      short8 af = *(const short8*)(smem + FP_OFF + swz2(prow, ks * 64 + lg * 16));
#pragma unroll
      for (int ct2 = 0; ct2 < 2; ++ct2) {
        int d = ch * 32 + ct2 * 16 + li;
        short8 bf = *(const short8*)(smem + FVT_OFF + swz1(d, ks * 64 + lg * 16));
        acco[ct2] = __builtin_amdgcn_mfma_f32_16x16x32_bf16(af, bf, acco[ct2], 0, 0, 0);
      }
    }
    __syncthreads();
  }

#pragma unroll
  for (int ct2 = 0; ct2 < 2; ++ct2) {
#pragma unroll
    for (int reg = 0; reg < 4; ++reg) {
      int rw = rh * 16 + lg * 4 + reg;
      int d = ch * 32 + ct2 * 16 + li;
      ctxp[(size_t)rw * D_HEAD + d] = acco[ct2][reg];
    }
  }
}

__global__ void __launch_bounds__(256, 4)
attn_kernel(const float* Q, const float* K, const float* V, const void* M,
            float* ctx, float* attn, const int* flag) {
  extern __shared__ char smem[];
  if (*flag)
    attn_body<true>(smem, Q, K, V, M, ctx, attn);
  else
    attn_body<false>(smem, Q, K, V, M, ctx, attn);
}

extern "C" void kernel_launch(void* const* d_in, const int* in_sizes, int n_in,
                              void* d_out, int out_size, void* d_ws, size_t ws_size,
                              hipStream_t stream) {
  const float* Q = (const float*)d_in[0];
  const float* K = (const float*)d_in[1];
  const float* V = (const float*)d_in[2];
  const void*  M = d_in[3];
  float* ctx  = (float*)d_out;
  float* attn = ctx + (size_t)NBH * S_LEN * D_HEAD;
  int* flag = (int*)d_ws;
  short* Kbf = (short*)((char*)d_ws + 256);
  short* Vtb = Kbf + (size_t)NBH * S_LEN * D_HEAD;
  const size_t PRE_BYTES = 256 + (size_t)2 * NBH * S_LEN * D_HEAD * sizeof(short);

  hipMemsetAsync(flag, 0, sizeof(int), stream);
  detect_mask_kernel<<<dim3(16), dim3(256), 0, stream>>>((const unsigned*)M, flag);

  if (ws_size >= PRE_BYTES) {
    convK_kernel<<<dim3(4096), dim3(256), 0, stream>>>(K, Kbf);
    convVT_kernel<<<dim3(32, 64), dim3(256), 0, stream>>>(V, Vtb);
    attn_fast_kernel<<<dim3(2048), dim3(256), 0, stream>>>(
        Q, M, Kbf, Vtb, ctx, attn, flag);
  } else {
    dim3 grid(S_LEN / 32, NBH);
    attn_kernel<<<grid, dim3(256), FSMEM_BYTES, stream>>>(
        Q, K, V, M, ctx, attn, flag);
  }
}

// Round 7
// 697.882 us; speedup vs baseline: 2.4536x; 2.4536x over previous
//
#include <hip/hip_runtime.h>
#include <hip/hip_bf16.h>
#include <stdint.h>

#define S_LEN 2048
#define D_HEAD 64
#define NBH 64            // B*H = 4*16
#define QBLK 32
#define KBLK 64
#define NITER (S_LEN / KBLK)   // 32

// Q pre-scale: 1/sqrt(64) * log2(e), so scores feed exp2f directly
#define QSCALE 0.1803368801111244f

typedef __attribute__((ext_vector_type(8))) short short8;  // 8 x bf16
typedef __attribute__((ext_vector_type(4))) float f32x4;

// ---------------- kernel A LDS layout ----------------
#define AKB   0        // 3 x 8KB K triple buffer
#define APRED 24576    // 8KB pred bytes: [iter 32][tid 256]
#define AP    32768    // 4KB Q staging
#define ALP   36864    // 256B row-sum partials
#define ASMEM 37120

// ---------------- kernel B LDS layout ----------------
#define BKB   0        // 3 x 8KB K triple buffer
#define BVT   24576    // 2 x 8KB Vt double buffer
#define BPRED 40960    // 8KB pred bytes
#define BP    49152    // 4KB P tile (Q staging in prologue)
#define BSMEM 53248

// ---------------- fallback LDS layout ----------------
#define FK_OFF  0
#define FVT_OFF 16384
#define FP_OFF  24576
#define FMB_OFF 28672
#define FLP_OFF 36864
#define FSMEM_BYTES 37120

__device__ __forceinline__ int swz1(int row, int b) {
  return row * 128 + (b ^ ((row & 7) << 4));
}
__device__ __forceinline__ int swz2(int row, int b) {
  return row * 128 + (b ^ (((row >> 1) & 7) << 4));
}

__device__ __forceinline__ short f2b(float x) {  // fp32 -> bf16 RNE
  unsigned u = __float_as_uint(x);
  unsigned r = 0x7FFFu + ((u >> 16) & 1u);
  return (short)((u + r) >> 16);
}

__device__ __forceinline__ void gload_lds16(const void* g, void* l) {
  __builtin_amdgcn_global_load_lds(
      (const __attribute__((address_space(1))) unsigned int*)g,
      (__attribute__((address_space(3))) unsigned int*)l, 16, 0, 0);
}

// counted-vmcnt barrier (T3/T4): loads stay in flight across the barrier
#define WAITBAR(N) do { \
  asm volatile("s_waitcnt vmcnt(" #N ") lgkmcnt(0)" ::: "memory"); \
  __builtin_amdgcn_s_barrier(); } while (0)

// Detect mask element width (int32 words are in {0,1,0x3F800000}).
__global__ void detect_mask_kernel(const unsigned* m, int* flag) {
  unsigned v = m[blockIdx.x * 256 + threadIdx.x];
  if (v != 0u && v != 1u && v != 0x3F800000u) atomicOr(flag, 1);
}

// fp32 -> bf16, linear (for K)
__global__ void __launch_bounds__(256) convK_kernel(
    const float* __restrict__ in, short* __restrict__ out) {
  size_t i = ((size_t)blockIdx.x * 256 + threadIdx.x) * 8;
  float4 a = ((const float4*)(in + i))[0];
  float4 b = ((const float4*)(in + i))[1];
  short8 v;
  v[0] = f2b(a.x); v[1] = f2b(a.y); v[2] = f2b(a.z); v[3] = f2b(a.w);
  v[4] = f2b(b.x); v[5] = f2b(b.y); v[6] = f2b(b.z); v[7] = f2b(b.w);
  *(short8*)(out + i) = v;
}

// fp32 V[bh][s][d] -> bf16 Vt[bh][d][s]
__global__ void __launch_bounds__(256) convVT_kernel(
    const float* __restrict__ V, short* __restrict__ out) {
  __shared__ __align__(16) short t[64 * 72];
  int tid = threadIdx.x;
  int kb = blockIdx.x * 64, bh = blockIdx.y;
  const float* src = V + ((size_t)bh * S_LEN + kb) * D_HEAD;
#pragma unroll
  for (int j = 0; j < 4; ++j) {
    int key = j * 16 + (tid >> 4), d0 = (tid & 15) * 4;
    float4 f = *(const float4*)(src + (size_t)key * D_HEAD + d0);
    t[(d0 + 0) * 72 + key] = f2b(f.x);
    t[(d0 + 1) * 72 + key] = f2b(f.y);
    t[(d0 + 2) * 72 + key] = f2b(f.z);
    t[(d0 + 3) * 72 + key] = f2b(f.w);
  }
  __syncthreads();
  int row = tid >> 2, seg = tid & 3;
  short8 v0 = *(const short8*)(t + row * 72 + seg * 16);
  short8 v1 = *(const short8*)(t + row * 72 + seg * 16 + 8);
  short* dst = out + (size_t)bh * D_HEAD * S_LEN + (size_t)row * S_LEN + kb + seg * 16;
  *(short8*)dst = v0;
  *(short8*)(dst + 8) = v1;
}

// ======================= KERNEL A: denominators + pred bits =======================
template <bool BYTEMASK>
__device__ __forceinline__ void pass1_body(
    char* smem, const float* Qg, const void* maskg, const short* Kbf,
    unsigned char* predg, float* linvg, int qb, int bh, int sidx) {

  const int tid = threadIdx.x;
  const int w = tid >> 6, l = tid & 63;
  const int lg = l >> 4, li = l & 15;
  const int rh = w >> 1, ch = w & 1;
  const int qbase = qb * QBLK;
  const int row = tid >> 3, seg = tid & 7;

  const float* Qp = Qg + ((size_t)bh * S_LEN + qbase) * D_HEAD;
  const short* Kbp = Kbf + (size_t)bh * S_LEN * D_HEAD;
  const size_t mbase = ((size_t)bh * S_LEN + qbase + row) * S_LEN + seg * 8;

  auto stageK = [&](int it) {               // -> kb[it % 3]
    const int buf = it % 3;
    const int r0 = w * 16 + (l >> 3), ci = l & 7;
#pragma unroll
    for (int j = 0; j < 2; ++j) {
      int r = r0 + j * 8;
      const short* src = Kbp + ((size_t)(it * KBLK + r)) * D_HEAD + ((ci ^ (r & 7)) * 8);
      int off = __builtin_amdgcn_readfirstlane(buf * 8192 + (w * 16 + j * 8) * 128);
      gload_lds16(src, smem + AKB + off);
    }
  };
  auto qkt = [&](f32x4* accs, const short8* qf, int it) {
    char* kb = smem + AKB + (it % 3) * 8192;
#pragma unroll
    for (int ct = 0; ct < 2; ++ct) {
      int key = ch * 32 + ct * 16 + li;
      short8 b0 = *(const short8*)(kb + swz1(key, lg * 16));
      short8 b1 = *(const short8*)(kb + swz1(key, 64 + lg * 16));
      accs[ct] = __builtin_amdgcn_mfma_f32_16x16x32_bf16(qf[0], b0, accs[ct], 0, 0, 0);
      accs[ct] = __builtin_amdgcn_mfma_f32_16x16x32_bf16(qf[1], b1, accs[ct], 0, 0, 0);
    }
  };

  struct MaskRegs { int4 a, b; uint2 c; };
  auto loadMask = [&](int it, MaskRegs& m) {
    if constexpr (BYTEMASK) {
      m.c = *(const uint2*)((const unsigned char*)maskg + mbase + it * KBLK);
    } else {
      const int* p = (const int*)maskg + mbase + it * KBLK;
      m.a = *(const int4*)p;
      m.b = *(const int4*)(p + 4);
    }
  };
  auto predWrite = [&](int it, const MaskRegs& m) {
    unsigned pb = 0;
    if constexpr (BYTEMASK) {
      unsigned lo = m.c.x, hi = m.c.y;
#pragma unroll
      for (int j = 0; j < 4; ++j) {
        pb |= (((lo >> (8 * j)) & 255u) != 0u ? 1u : 0u) << j;
        pb |= (((hi >> (8 * j)) & 255u) != 0u ? 1u : 0u) << (j + 4);
      }
    } else {
      pb |= (m.a.x != 0) ? 1u : 0u;
      pb |= (m.a.y != 0) ? 2u : 0u;
      pb |= (m.a.z != 0) ? 4u : 0u;
      pb |= (m.a.w != 0) ? 8u : 0u;
      pb |= (m.b.x != 0) ? 16u : 0u;
      pb |= (m.b.y != 0) ? 32u : 0u;
      pb |= (m.b.z != 0) ? 64u : 0u;
      pb |= (m.b.w != 0) ? 128u : 0u;
    }
    *(unsigned char*)(smem + APRED + it * 256 + row * 8 + seg) = (unsigned char)pb;
  };

  // ---- prologue ----
  MaskRegs t0, t1, mA, mB;
  loadMask(0, t0); loadMask(1, t1); loadMask(2, mA); loadMask(3, mB);
  stageK(0); stageK(1);
  {
    const float* src = Qp + row * D_HEAD + seg * 8;
    float4 a = ((const float4*)src)[0];
    float4 b = ((const float4*)src)[1];
    short8 v;
    v[0] = f2b(a.x * QSCALE); v[1] = f2b(a.y * QSCALE);
    v[2] = f2b(a.z * QSCALE); v[3] = f2b(a.w * QSCALE);
    v[4] = f2b(b.x * QSCALE); v[5] = f2b(b.y * QSCALE);
    v[6] = f2b(b.z * QSCALE); v[7] = f2b(b.w * QSCALE);
    *(short8*)(smem + AP + swz1(row, seg * 16)) = v;
  }
  __syncthreads();   // Q visible; drains vmcnt(0) -> sK(0), sK(1) complete
  short8 qfrag[2];
  {
    int qr = rh * 16 + li;
    qfrag[0] = *(const short8*)(smem + AP + swz1(qr, lg * 16));
    qfrag[1] = *(const short8*)(smem + AP + swz1(qr, 64 + lg * 16));
  }
  predWrite(0, t0);
  predWrite(1, t1);

  // ---- main loop ----
  float l_acc[4] = {0.f, 0.f, 0.f, 0.f};
  auto p1iter = [&](int i, MaskRegs& m) {
    f32x4 accs[2] = {{0.f,0.f,0.f,0.f},{0.f,0.f,0.f,0.f}};
    qkt(accs, qfrag, i);
    if (i <= 27) {
      if constexpr (BYTEMASK) WAITBAR(1); else WAITBAR(2);
    } else {
      WAITBAR(0);
    }
    if (i + 2 < NITER) stageK(i + 2);
    if (i + 2 < NITER) predWrite(i + 2, m);
    if (i + 4 < NITER) loadMask(i + 4, m);
#pragma unroll
    for (int reg = 0; reg < 4; ++reg) {
      int rw = rh * 16 + lg * 4 + reg;
      unsigned long long p64 =
          *(const unsigned long long*)(smem + APRED + i * 256 + rw * 8);
      unsigned pw = (unsigned)(p64 >> (ch << 5));
      float e0 = ((pw >> li) & 1u)        ? 0.f : exp2f(accs[0][reg]);
      float e1 = ((pw >> (16 + li)) & 1u) ? 0.f : exp2f(accs[1][reg]);
      float s = e0 + e1;
      s += __shfl_xor(s, 1);
      s += __shfl_xor(s, 2);
      s += __shfl_xor(s, 4);
      s += __shfl_xor(s, 8);
      l_acc[reg] += s;
    }
  };
  for (int i = 0; i < NITER; i += 2) {
    p1iter(i, mA);
    p1iter(i + 1, mB);
  }

  // ---- epilogue: linv + pred dump ----
  if (li == 0) {
#pragma unroll
    for (int reg = 0; reg < 4; ++reg)
      *(float*)(smem + ALP + ch * 128 + (rh * 16 + lg * 4 + reg) * 4) = l_acc[reg];
  }
  __syncthreads();
  if (ch == 0 && li == 0) {
#pragma unroll
    for (int reg = 0; reg < 4; ++reg) {
      int rw = rh * 16 + lg * 4 + reg;
      float tot = *(const float*)(smem + ALP + rw * 4) +
                  *(const float*)(smem + ALP + 128 + rw * 4);
      linvg[(size_t)bh * S_LEN + qbase + rw] = 1.0f / tot;
    }
  }
  unsigned char* pd = predg + (size_t)sidx * 8192;
  *(uint4*)(pd + tid * 16) = *(const uint4*)(smem + APRED + tid * 16);
  *(uint4*)(pd + 4096 + tid * 16) = *(const uint4*)(smem + APRED + 4096 + tid * 16);
}

__global__ void __launch_bounds__(256, 4)
attn_pass1_kernel(const float* Q, const void* M, const short* Kbf,
                  unsigned char* predg, float* linvg, const int* flag) {
  __shared__ __align__(16) char smem[ASMEM];
  int bid = blockIdx.x;
  int s = ((bid & 7) << 9) | (bid >> 3);   // XCD-bijective swizzle (4096 = 8*512)
  int bh = s >> 6, qb = s & 63;
  if (*flag)
    pass1_body<true>(smem, Q, M, Kbf, predg, linvg, qb, bh, s);
  else
    pass1_body<false>(smem, Q, M, Kbf, predg, linvg, qb, bh, s);
}

// ======================= KERNEL B: attn + ctx =======================
__global__ void __launch_bounds__(256, 3)
attn_pass2_kernel(const float* Qg, const short* Kbf, const short* Vtb,
                  const unsigned char* predg, const float* linvg,
                  float* ctxg, float* attng) {
  __shared__ __align__(16) char smem[BSMEM];
  const int tid = threadIdx.x;
  const int w = tid >> 6, l = tid & 63;
  const int lg = l >> 4, li = l & 15;
  const int rh = w >> 1, ch = w & 1;
  int bid = blockIdx.x;
  int s = ((bid & 7) << 9) | (bid >> 3);
  int bh = s >> 6, qb = s & 63;
  const int qbase = qb * QBLK;
  const int row = tid >> 3, seg = tid & 7;

  const float* Qp = Qg + ((size_t)bh * S_LEN + qbase) * D_HEAD;
  const short* Kbp = Kbf + (size_t)bh * S_LEN * D_HEAD;
  const short* Vtp = Vtb + (size_t)bh * D_HEAD * S_LEN;
  float* attnp = attng + ((size_t)bh * S_LEN + qbase) * S_LEN;
  float* ctxp  = ctxg  + ((size_t)bh * S_LEN + qbase) * D_HEAD;

  auto stageK = [&](int it) {               // -> kb[it % 3]
    const int buf = it % 3;
    const int r0 = w * 16 + (l >> 3), ci = l & 7;
#pragma unroll
    for (int j = 0; j < 2; ++j) {
      int r = r0 + j * 8;
      const short* src = Kbp + ((size_t)(it * KBLK + r)) * D_HEAD + ((ci ^ (r & 7)) * 8);
      int off = __builtin_amdgcn_readfirstlane(buf * 8192 + (w * 16 + j * 8) * 128);
      gload_lds16(src, smem + BKB + off);
    }
  };
  auto stageVt = [&](int it) {              // -> vt[it & 1]
    const int buf = it & 1;
    const int d0 = w * 16 + (l >> 3), ci = l & 7;
#pragma unroll
    for (int j = 0; j < 2; ++j) {
      int d = d0 + j * 8;
      const short* src = Vtp + (size_t)d * S_LEN + it * KBLK + ((ci ^ (d & 7)) * 8);
      int off = __builtin_amdgcn_readfirstlane(buf * 8192 + (w * 16 + j * 8) * 128);
      gload_lds16(src, smem + BVT + off);
    }
  };
  auto qkt = [&](f32x4* accs, const short8* qf, int it) {
    char* kb = smem + BKB + (it % 3) * 8192;
#pragma unroll
    for (int ct = 0; ct < 2; ++ct) {
      int key = ch * 32 + ct * 16 + li;
      short8 b0 = *(const short8*)(kb + swz1(key, lg * 16));
      short8 b1 = *(const short8*)(kb + swz1(key, 64 + lg * 16));
      accs[ct] = __builtin_amdgcn_mfma_f32_16x16x32_bf16(qf[0], b0, accs[ct], 0, 0, 0);
      accs[ct] = __builtin_amdgcn_mfma_f32_16x16x32_bf16(qf[1], b1, accs[ct], 0, 0, 0);
    }
  };

  // ---- prologue ----
  stageK(0); stageK(1);
  const unsigned char* pd = predg + (size_t)s * 8192;
  uint4 pg0 = *(const uint4*)(pd + tid * 16);
  uint4 pg1 = *(const uint4*)(pd + 4096 + tid * 16);
  {
    const float* src = Qp + row * D_HEAD + seg * 8;
    float4 a = ((const float4*)src)[0];
    float4 b = ((const float4*)src)[1];
    short8 v;
    v[0] = f2b(a.x * QSCALE); v[1] = f2b(a.y * QSCALE);
    v[2] = f2b(a.z * QSCALE); v[3] = f2b(a.w * QSCALE);
    v[4] = f2b(b.x * QSCALE); v[5] = f2b(b.y * QSCALE);
    v[6] = f2b(b.z * QSCALE); v[7] = f2b(b.w * QSCALE);
    *(short8*)(smem + BP + swz1(row, seg * 16)) = v;
  }
  __syncthreads();   // Q visible; drains all loads (K0,K1 in LDS, pg in regs)
  short8 qfrag[2];
  {
    int qr = rh * 16 + li;
    qfrag[0] = *(const short8*)(smem + BP + swz1(qr, lg * 16));
    qfrag[1] = *(const short8*)(smem + BP + swz1(qr, 64 + lg * 16));
  }
  *(uint4*)(smem + BPRED + tid * 16) = pg0;
  *(uint4*)(smem + BPRED + 4096 + tid * 16) = pg1;
  float linv[4];
#pragma unroll
  for (int reg = 0; reg < 4; ++reg)
    linv[reg] = linvg[(size_t)bh * S_LEN + qbase + rh * 16 + lg * 4 + reg];
  float* attnrow[4];
#pragma unroll
  for (int reg = 0; reg < 4; ++reg)
    attnrow[reg] = attnp + (size_t)(rh * 16 + lg * 4 + reg) * S_LEN + ch * 32 + li;
  stageVt(0);
  asm volatile("s_waitcnt lgkmcnt(0)" ::: "memory");  // PRED visible, qfrag read done
  __builtin_amdgcn_s_barrier();

  // ---- main loop (R4 pass-2 structure, audited WAITBAR constants) ----
  f32x4 acco[2] = {{0.f,0.f,0.f,0.f},{0.f,0.f,0.f,0.f}};
  for (int i = 0; i < NITER; ++i) {
    f32x4 accs[2] = {{0.f,0.f,0.f,0.f},{0.f,0.f,0.f,0.f}};
    qkt(accs, qfrag, i);
    // BARRIER_A: P-tile WAR fence (all waves' prior PV ds_reads done)
    asm volatile("s_waitcnt lgkmcnt(0)" ::: "memory");
    __builtin_amdgcn_s_barrier();
    if (i + 2 < NITER) stageK(i + 2);
    if (i + 1 < NITER) stageVt(i + 1);
#pragma unroll
    for (int reg = 0; reg < 4; ++reg) {
      int rw = rh * 16 + lg * 4 + reg;
      unsigned long long p64 =
          *(const unsigned long long*)(smem + BPRED + i * 256 + rw * 8);
      unsigned pw = (unsigned)(p64 >> (ch << 5));
      float e0 = ((pw >> li) & 1u)        ? 0.f : exp2f(accs[0][reg]) * linv[reg];
      float e1 = ((pw >> (16 + li)) & 1u) ? 0.f : exp2f(accs[1][reg]) * linv[reg];
      attnrow[reg][i * KBLK] = e0;         // 16-lane x 4B = full 64B lines
      attnrow[reg][i * KBLK + 16] = e1;
      *(short*)(smem + BP + swz2(rw, (ch * 32 + li) * 2)) = f2b(e0);
      *(short*)(smem + BP + swz2(rw, (ch * 32 + 16 + li) * 2)) = f2b(e1);
    }
    // BARRIER_B: P visible; K(i+1)/Vt(i) drained, newer loads/stores in flight
    if (i == 0) WAITBAR(12);
    else if (i <= 29) WAITBAR(20);
    else WAITBAR(8);
    // PV: O(16x32 per wave) += P(16x64) * V(64xD tile)
    {
      char* vb = smem + BVT + (i & 1) * 8192;
#pragma unroll
      for (int ks = 0; ks < 2; ++ks) {
        int prow = rh * 16 + li;
        short8 af = *(const short8*)(smem + BP + swz2(prow, ks * 64 + lg * 16));
#pragma unroll
        for (int ct2 = 0; ct2 < 2; ++ct2) {
          int d = ch * 32 + ct2 * 16 + li;
          short8 bf = *(const short8*)(vb + swz1(d, ks * 64 + lg * 16));
          acco[ct2] = __builtin_amdgcn_mfma_f32_16x16x32_bf16(af, bf, acco[ct2], 0, 0, 0);
        }
      }
    }
  }

  // ---- epilogue: P was normalized, ctx = acco ----
#pragma unroll
  for (int ct2 = 0; ct2 < 2; ++ct2)
#pragma unroll
    for (int reg = 0; reg < 4; ++reg) {
      int rw = rh * 16 + lg * 4 + reg;
      int d = ch * 32 + ct2 * 16 + li;
      ctxp[(size_t)rw * D_HEAD + d] = acco[ct2][reg];
    }
}

// ======================= FALLBACK (round-2 body; no workspace needed) =======================
template <bool BYTEMASK>
__device__ __forceinline__ void attn_body(
    char* smem, const float* Qg, const float* Kg, const float* Vg,
    const void* maskg, float* ctxg, float* attng) {

  const int tid = threadIdx.x;
  const int w = tid >> 6, l = tid & 63;
  const int lg = l >> 4, li = l & 15;
  const int rh = w >> 1, ch = w & 1;
  const int qb = blockIdx.x, bh = blockIdx.y;
  const int qbase = qb * 32;

  const float* Qp = Qg + ((size_t)bh * S_LEN + qbase) * D_HEAD;
  const float* Kp = Kg + (size_t)bh * S_LEN * D_HEAD;
  const float* Vp = Vg + (size_t)bh * S_LEN * D_HEAD;
  float* attnp = attng + ((size_t)bh * S_LEN + qbase) * S_LEN;
  float* ctxp  = ctxg  + ((size_t)bh * S_LEN + qbase) * D_HEAD;
  const size_t mrow0 = ((size_t)bh * S_LEN + qbase) * S_LEN;

  auto stageK = [&](int it, int buf) {
    char* kb = smem + FK_OFF + buf * 8192;
    int key = tid >> 2, seg = tid & 3;
    const float* src = Kp + ((size_t)(it * KBLK + key)) * D_HEAD + seg * 16;
    float4 f0 = ((const float4*)src)[0];
    float4 f1 = ((const float4*)src)[1];
    float4 f2 = ((const float4*)src)[2];
    float4 f3 = ((const float4*)src)[3];
    short8 v0, v1;
    v0[0] = f2b(f0.x); v0[1] = f2b(f0.y); v0[2] = f2b(f0.z); v0[3] = f2b(f0.w);
    v0[4] = f2b(f1.x); v0[5] = f2b(f1.y); v0[6] = f2b(f1.z); v0[7] = f2b(f1.w);
    v1[0] = f2b(f2.x); v1[1] = f2b(f2.y); v1[2] = f2b(f2.z); v1[3] = f2b(f2.w);
    v1[4] = f2b(f3.x); v1[5] = f2b(f3.y); v1[6] = f2b(f3.z); v1[7] = f2b(f3.w);
    *(short8*)(kb + swz1(key, seg * 32)) = v0;
    *(short8*)(kb + swz1(key, seg * 32 + 16)) = v1;
  };

  auto stageVt = [&](int it) {
    char* vb = smem + FVT_OFF;
    int key = l, db = w;
    const float* src = Vp + ((size_t)(it * KBLK + key)) * D_HEAD + db * 16;
#pragma unroll
    for (int j = 0; j < 4; ++j) {
      float4 f = ((const float4*)src)[j];
      int dd = db * 16 + j * 4;
      *(short*)(vb + swz1(dd + 0, key * 2)) = f2b(f.x);
      *(short*)(vb + swz1(dd + 1, key * 2)) = f2b(f.y);
      *(short*)(vb + swz1(dd + 2, key * 2)) = f2b(f.z);
      *(short*)(vb + swz1(dd + 3, key * 2)) = f2b(f.w);
    }
  };

  auto loadMask = [&](int it, unsigned* m) {
#pragma unroll
    for (int reg = 0; reg < 4; ++reg) {
      int rw = rh * 16 + lg * 4 + reg;
#pragma unroll
      for (int ct = 0; ct < 2; ++ct) {
        size_t idx = mrow0 + (size_t)rw * S_LEN + it * KBLK + ch * 32 + ct * 16 + li;
        if constexpr (BYTEMASK)
          m[ct * 4 + reg] = (unsigned)((const unsigned char*)maskg)[idx];
        else
          m[ct * 4 + reg] = ((const unsigned*)maskg)[idx];
      }
    }
  };

  auto qkt = [&](f32x4* accs, const short8* qf, int buf) {
    char* kb = smem + FK_OFF + buf * 8192;
#pragma unroll
    for (int ct = 0; ct < 2; ++ct) {
      int key = ch * 32 + ct * 16 + li;
      short8 b0 = *(const short8*)(kb + swz1(key, lg * 16));
      short8 b1 = *(const short8*)(kb + swz1(key, 64 + lg * 16));
      accs[ct] = __builtin_amdgcn_mfma_f32_16x16x32_bf16(qf[0], b0, accs[ct], 0, 0, 0);
      accs[ct] = __builtin_amdgcn_mfma_f32_16x16x32_bf16(qf[1], b1, accs[ct], 0, 0, 0);
    }
  };

  stageK(0, 0);
  unsigned mc[8];
  loadMask(0, mc);
  {
    int rw = tid >> 3, seg = tid & 7;
    const float* src = Qp + rw * D_HEAD + seg * 8;
    float4 a = ((const float4*)src)[0];
    float4 b = ((const float4*)src)[1];
    short8 v;
    v[0] = f2b(a.x); v[1] = f2b(a.y); v[2] = f2b(a.z); v[3] = f2b(a.w);
    v[4] = f2b(b.x); v[5] = f2b(b.y); v[6] = f2b(b.z); v[7] = f2b(b.w);
    *(short8*)(smem + FP_OFF + swz1(rw, seg * 16)) = v;
  }
  __syncthreads();
  short8 qfrag[2];
  {
    int rw = rh * 16 + li;
    qfrag[0] = *(const short8*)(smem + FP_OFF + swz1(rw, lg * 16));
    qfrag[1] = *(const short8*)(smem + FP_OFF + swz1(rw, 64 + lg * 16));
  }
  __syncthreads();

  float l_acc[4] = {0.f, 0.f, 0.f, 0.f};
  for (int it = 0; it < NITER; ++it) {
    const int cb = it & 1, nb = cb ^ 1;
    if (it + 1 < NITER) stageK(it + 1, nb);
    unsigned mn[8];
    if (it + 1 < NITER) loadMask(it + 1, mn);
    f32x4 accs[2] = {{0.f,0.f,0.f,0.f},{0.f,0.f,0.f,0.f}};
    qkt(accs, qfrag, cb);
    unsigned mbyte = 0;
#pragma unroll
    for (int reg = 0; reg < 4; ++reg) {
      float contrib = 0.f;
#pragma unroll
      for (int ct = 0; ct < 2; ++ct) {
        bool pred = mc[ct * 4 + reg] != 0u;
        mbyte |= (unsigned)pred << (ct * 4 + reg);
        float pp = pred ? 0.f : __expf(accs[ct][reg] * 0.125f);
        contrib += pp;
      }
      contrib += __shfl_xor(contrib, 1);
      contrib += __shfl_xor(contrib, 2);
      contrib += __shfl_xor(contrib, 4);
      contrib += __shfl_xor(contrib, 8);
      l_acc[reg] += contrib;
    }
    *(unsigned char*)(smem + FMB_OFF + it * 256 + tid) = (unsigned char)mbyte;
    __syncthreads();
    if (it + 1 < NITER) {
#pragma unroll
      for (int i = 0; i < 8; ++i) mc[i] = mn[i];
    }
  }

  if (li == 0) {
#pragma unroll
    for (int reg = 0; reg < 4; ++reg)
      *(float*)(smem + FLP_OFF + ch * 128 + (rh * 16 + lg * 4 + reg) * 4) = l_acc[reg];
  }
  stageK(0, 0);
  stageVt(0);
  __syncthreads();
  float linv[4];
#pragma unroll
  for (int reg = 0; reg < 4; ++reg) {
    int rw = rh * 16 + lg * 4 + reg;
    linv[reg] = 1.0f / (*(const float*)(smem + FLP_OFF + rw * 4) +
                        *(const float*)(smem + FLP_OFF + 128 + rw * 4));
  }

  f32x4 acco[2] = {{0.f,0.f,0.f,0.f},{0.f,0.f,0.f,0.f}};
  for (int it = 0; it < NITER; ++it) {
    const int cb = it & 1, nb = cb ^ 1;
    if (it > 0) stageVt(it);
    if (it + 1 < NITER) stageK(it + 1, nb);
    f32x4 accs[2] = {{0.f,0.f,0.f,0.f},{0.f,0.f,0.f,0.f}};
    qkt(accs, qfrag, cb);
    unsigned mbyte = *(const unsigned char*)(smem + FMB_OFF + it * 256 + tid);
#pragma unroll
    for (int reg = 0; reg < 4; ++reg) {
      int rw = rh * 16 + lg * 4 + reg;
#pragma unroll
      for (int ct = 0; ct < 2; ++ct) {
        int col = ch * 32 + ct * 16 + li;
        bool pred = (mbyte >> (ct * 4 + reg)) & 1u;
        float pp = pred ? 0.f : __expf(accs[ct][reg] * 0.125f) * linv[reg];
        attnp[(size_t)rw * S_LEN + it * KBLK + col] = pp;
        *(short*)(smem + FP_OFF + swz2(rw, col * 2)) = f2b(pp);
      }
    }
    __syncthreads();
#pragma unroll
    for (int ks = 0; ks < 2; ++ks) {
      int prow = rh * 16 + li;
      short8 af = *(const short8*)(smem + FP_OFF + swz2(prow, ks * 64 + lg * 16));
#pragma unroll
      for (int ct2 = 0; ct2 < 2; ++ct2) {
        int d = ch * 32 + ct2 * 16 + li;
        short8 bf = *(const short8*)(smem + FVT_OFF + swz1(d, ks * 64 + lg * 16));
        acco[ct2] = __builtin_amdgcn_mfma_f32_16x16x32_bf16(af, bf, acco[ct2], 0, 0, 0);
      }
    }
    __syncthreads();
  }

#pragma unroll
  for (int ct2 = 0; ct2 < 2; ++ct2) {
#pragma unroll
    for (int reg = 0; reg < 4; ++reg) {
      int rw = rh * 16 + lg * 4 + reg;
      int d = ch * 32 + ct2 * 16 + li;
      ctxp[(size_t)rw * D_HEAD + d] = acco[ct2][reg];
    }
  }
}

__global__ void __launch_bounds__(256, 4)
attn_kernel(const float* Q, const float* K, const float* V, const void* M,
            float* ctx, float* attn, const int* flag) {
  extern __shared__ char smem[];
  if (*flag)
    attn_body<true>(smem, Q, K, V, M, ctx, attn);
  else
    attn_body<false>(smem, Q, K, V, M, ctx, attn);
}

extern "C" void kernel_launch(void* const* d_in, const int* in_sizes, int n_in,
                              void* d_out, int out_size, void* d_ws, size_t ws_size,
                              hipStream_t stream) {
  const float* Q = (const float*)d_in[0];
  const float* K = (const float*)d_in[1];
  const float* V = (const float*)d_in[2];
  const void*  M = d_in[3];
  float* ctx  = (float*)d_out;
  float* attn = ctx + (size_t)NBH * S_LEN * D_HEAD;
  int* flag = (int*)d_ws;
  short* Kbf = (short*)((char*)d_ws + 256);
  short* Vtb = Kbf + (size_t)NBH * S_LEN * D_HEAD;
  float* linvg = (float*)(Vtb + (size_t)NBH * S_LEN * D_HEAD);
  // pred bits live in the ctx region of d_out: block s's 8KB pred slot is the
  // same 8KB that block s itself later overwrites with ctx (block-private).
  unsigned char* predg = (unsigned char*)ctx;
  const size_t PRE_BYTES = 256 + (size_t)2 * NBH * S_LEN * D_HEAD * sizeof(short)
                         + (size_t)NBH * S_LEN * sizeof(float);

  hipMemsetAsync(flag, 0, sizeof(int), stream);
  detect_mask_kernel<<<dim3(16), dim3(256), 0, stream>>>((const unsigned*)M, flag);

  if (ws_size >= PRE_BYTES) {
    convK_kernel<<<dim3(4096), dim3(256), 0, stream>>>(K, Kbf);
    convVT_kernel<<<dim3(32, 64), dim3(256), 0, stream>>>(V, Vtb);
    attn_pass1_kernel<<<dim3(4096), dim3(256), 0, stream>>>(
        Q, M, Kbf, predg, linvg, flag);
    attn_pass2_kernel<<<dim3(4096), dim3(256), 0, stream>>>(
        Q, Kbf, Vtb, predg, linvg, ctx, attn);
  } else {
    dim3 grid(S_LEN / 32, NBH);
    attn_kernel<<<grid, dim3(256), FSMEM_BYTES, stream>>>(
        Q, K, V, M, ctx, attn, flag);
  }
}